// Round 5
// baseline (122.803 us; speedup 1.0000x reference)
//
#include <hip/hip_runtime.h>
#include <hip/hip_bf16.h>

// Problem constants
#define BB 32
#define SS 256
#define DD 300
#define PDD 32
#define MM 66
#define FF 398      // D + PD + M
#define HH 6
#define G4 24       // 4*H
#define AA 12

__device__ __forceinline__ float fast_rcp(float x) { return __builtin_amdgcn_rcpf(x); }
__device__ __forceinline__ float sigmoidf_(float x) { return fast_rcp(1.f + __expf(-x)); }
__device__ __forceinline__ float fast_tanh(float x) {
    return 1.f - 2.f * fast_rcp(__expf(2.f * x) + 1.f);
}
__device__ __forceinline__ float bcast_lane(float x, int l) {
    return __int_as_float(__builtin_amdgcn_readlane(__float_as_int(x), l));
}

// -------------------------------------------------------------------------
// Kernel 1 (v3): embed+concat+input projection, both directions fused.
// 16 positions/block -> grid 512 (2 blocks/CU, 8 waves/CU).
// -------------------------------------------------------------------------
#define EP_POS 16
__global__ __launch_bounds__(256) void k_embed_proj(
    const int* __restrict__ words, const int* __restrict__ pos,
    const float* __restrict__ morph, const float* __restrict__ wtab,
    const float* __restrict__ ptab,
    const float* __restrict__ Wxf, const float* __restrict__ bfv,
    const float* __restrict__ Wxb, const float* __restrict__ bbv,
    float* __restrict__ xgf, float* __restrict__ xgb)
{
    __shared__ float sfeat[EP_POS * 100];   //  6.4 KB
    __shared__ float sW[48 * 100];          // 19.2 KB

    int t   = threadIdx.x;
    int bs0 = blockIdx.x * EP_POS;

    int cg = t & 15;         // col group: cols 3*cg .. 3*cg+2 (0..47)
    int p  = t >> 4;         // position 0..15
    float a0 = 0.f, a1 = 0.f, a2 = 0.f;

    for (int tile = 0; tile < 4; ++tile) {
        if (tile < 3) {
            for (int idx = t; idx < EP_POS * 25; idx += 256) {
                int pp = idx / 25, f = idx % 25;
                const float4* srcr = (const float4*)(wtab +
                    (size_t)words[bs0 + pp] * DD + tile * 100);
                ((float4*)sfeat)[pp * 25 + f] = srcr[f];
            }
        } else {
            for (int idx = t; idx < EP_POS * 100; idx += 256) {
                int pp = idx / 100, kk = idx % 100;
                float vv;
                if (kk < PDD)           vv = ptab[pos[bs0 + pp] * PDD + kk];
                else if (kk < PDD + MM) vv = morph[(size_t)(bs0 + pp) * MM + (kk - PDD)];
                else                    vv = 0.f;
                sfeat[pp * 100 + kk] = vv;
            }
        }
        for (int idx = t; idx < 2400; idx += 256) {
            int kk = idx / 24, j = idx % 24;
            int k = tile * 100 + kk;
            float wf = (k < FF) ? Wxf[k * G4 + j] : 0.f;
            float wb = (k < FF) ? Wxb[k * G4 + j] : 0.f;
            sW[j * 100 + kk]        = wf;
            sW[(24 + j) * 100 + kk] = wb;
        }
        __syncthreads();

        const float4* Fp = (const float4*)(sfeat + p * 100);
        const float4* W0 = (const float4*)(sW + (3 * cg + 0) * 100);
        const float4* W1 = (const float4*)(sW + (3 * cg + 1) * 100);
        const float4* W2 = (const float4*)(sW + (3 * cg + 2) * 100);
        #pragma unroll 5
        for (int q = 0; q < 25; ++q) {
            float4 f0 = Fp[q];
            float4 w0 = W0[q], w1 = W1[q], w2 = W2[q];
            a0 = fmaf(f0.x, w0.x, a0); a0 = fmaf(f0.y, w0.y, a0);
            a0 = fmaf(f0.z, w0.z, a0); a0 = fmaf(f0.w, w0.w, a0);
            a1 = fmaf(f0.x, w1.x, a1); a1 = fmaf(f0.y, w1.y, a1);
            a1 = fmaf(f0.z, w1.z, a1); a1 = fmaf(f0.w, w1.w, a1);
            a2 = fmaf(f0.x, w2.x, a2); a2 = fmaf(f0.y, w2.y, a2);
            a2 = fmaf(f0.z, w2.z, a2); a2 = fmaf(f0.w, w2.w, a2);
        }
        __syncthreads();
    }

    int c0  = 3 * cg;
    int dir = c0 >= 24 ? 1 : 0;
    int jj  = c0 - dir * 24;
    const float* bias = dir ? bbv : bfv;
    float*       xg   = dir ? xgb : xgf;
    float* o = xg + (size_t)(bs0 + p) * G4 + jj;
    o[0] = a0 + bias[jj]; o[1] = a1 + bias[jj + 1]; o[2] = a2 + bias[jj + 2];
}

// -------------------------------------------------------------------------
// Kernel 2 (v4): LSTM recurrence.
// 8 blocks x 512 threads; wave w = one (b,dir) chain -> 2 waves/SIMD so
// stalls overlap across chains. Gate inputs read DIRECTLY from global
// (L2-warm) with a 4-step rotating register prefetch (all addresses are
// base + compile-time immediates via the SST template). h written to a
// per-wave LDS slice, bulk-copied coalesced at the end.
// -------------------------------------------------------------------------
template<int SST>
__device__ __forceinline__ void lstm_chain(
    const float* __restrict__ px,     // xg + s0*G4 + k (per-lane)
    const float* __restrict__ Wh, int k, int lane,
    float* __restrict__ hb)           // per-wave hbuf slice (logical order)
{
    float wh0[HH], wh1[HH], wh2[HH], wh3[HH];
    #pragma unroll
    for (int m = 0; m < HH; ++m) {
        wh0[m] = Wh[m * G4 + 0 * HH + k];
        wh1[m] = Wh[m * G4 + 1 * HH + k];
        wh2[m] = Wh[m * G4 + 2 * HH + k];
        wh3[m] = Wh[m * G4 + 3 * HH + k];
    }
    float sh[HH];
    #pragma unroll
    for (int m = 0; m < HH; ++m) sh[m] = 0.f;
    float c = 0.f;
    bool wr = lane < HH;

    // 4-step rotating prefetch buffer
    float pgi[4], pgf[4], pgc[4], pgo[4];
    #pragma unroll
    for (int sl = 0; sl < 4; ++sl) {
        const float* p = px + SST * G4 * sl;
        pgi[sl] = p[0]; pgf[sl] = p[HH]; pgc[sl] = p[2 * HH]; pgo[sl] = p[3 * HH];
    }

    #pragma unroll 1
    for (int t = 0; t < SS; t += 4) {
        #pragma unroll
        for (int sl = 0; sl < 4; ++sl) {
            float gi = pgi[sl], gf = pgf[sl], gc = pgc[sl], go = pgo[sl];
            // prefetch step t+4+sl (last iter overreads by <=4 steps; lands in
            // the adjacent xg/ws arrays -- safe, values unused)
            const float* p = px + SST * G4 * (t + 4 + sl);
            pgi[sl] = p[0]; pgf[sl] = p[HH]; pgc[sl] = p[2 * HH]; pgo[sl] = p[3 * HH];

            #pragma unroll
            for (int m = 0; m < HH; ++m) {
                gf = fmaf(sh[m], wh1[m], gf);
                gc = fmaf(sh[m], wh2[m], gc);
                gi = fmaf(sh[m], wh0[m], gi);
                go = fmaf(sh[m], wh3[m], go);
            }
            c = sigmoidf_(gf) * c + sigmoidf_(gi) * fast_tanh(gc);
            float h = sigmoidf_(go) * fast_tanh(c);
            if (wr) hb[(t + sl) * HH + k] = h;
            #pragma unroll
            for (int m = 0; m < HH; ++m) sh[m] = bcast_lane(h, m);
        }
    }
}

__global__ __launch_bounds__(512) void k_lstm(
    const float* __restrict__ xgf, const float* __restrict__ xgb,
    const float* __restrict__ Whf, const float* __restrict__ Whb,
    float* __restrict__ repr)
{
    __shared__ float hbuf[8 * SS * HH];     // 48 KB
    int widx = threadIdx.x >> 6;
    int lane = threadIdx.x & 63;
    int chain = blockIdx.x * 8 + widx;      // 0..63
    int dir = chain >> 5;
    int b   = chain & 31;
    int k   = lane % HH;

    const float* xg = (dir ? xgb : xgf) + (size_t)b * SS * G4;
    const float* Wh = dir ? Whb : Whf;
    float* hb = hbuf + widx * (SS * HH);

    if (dir == 0) lstm_chain< 1>(xg + 0 * G4 + k,          Wh, k, lane, hb);
    else          lstm_chain<-1>(xg + (SS - 1) * G4 + k,   Wh, k, lane, hb);

    // coalesced copy out (undo time order for bwd); same-wave LDS dep ->
    // compiler inserts the lgkmcnt wait.
    for (int u = 0; u < (SS * HH) / 64; ++u) {
        int idx = lane + u * 64;
        int tt = idx / 6, cc = idx - tt * 6;
        int s = dir ? (SS - 1 - tt) : tt;
        repr[((size_t)b * SS + s) * (2 * HH) + dir * HH + cc] = hb[idx];
    }
}

// -------------------------------------------------------------------------
// Kernel 3: ua = repr@Wu+bu ; wa = repr@Ww+bw. One thread per (b,s).
// -------------------------------------------------------------------------
__global__ __launch_bounds__(256) void k_uawa(
    const float* __restrict__ repr,
    const float* __restrict__ Wu, const float* __restrict__ bu,
    const float* __restrict__ Ww, const float* __restrict__ bw,
    float* __restrict__ ua, float* __restrict__ wa)
{
    int bs = blockIdx.x * blockDim.x + threadIdx.x;   // 0..8191
    float r[AA];
    #pragma unroll
    for (int e = 0; e < AA; ++e) r[e] = repr[(size_t)bs * AA + e];
    #pragma unroll
    for (int d = 0; d < AA; ++d) {
        float au = bu[d], aw = bw[d];
        #pragma unroll
        for (int e = 0; e < AA; ++e) {
            au = fmaf(r[e], Wu[e * AA + d], au);
            aw = fmaf(r[e], Ww[e * AA + d], aw);
        }
        ua[(size_t)bs * AA + d] = au;
        wa[(size_t)bs * AA + d] = aw;
    }
}

// -------------------------------------------------------------------------
// Kernel 4: arc scores + sum-exp + CE partials + exp table.
// -------------------------------------------------------------------------
__global__ __launch_bounds__(256) void k_score(
    const float* __restrict__ ua, const float* __restrict__ wa,
    const float* __restrict__ v, const int* __restrict__ heads,
    float* __restrict__ out, float* __restrict__ ce)
{
    int bi = blockIdx.x;            // b*S + i
    int i  = bi & 255;
    int j  = threadIdx.x;

    __shared__ float swa[AA], sv[AA];
    if (j < AA) { swa[j] = wa[(size_t)bi * AA + j]; sv[j] = v[j]; }
    __syncthreads();

    const float* uj = ua + ((size_t)(bi & ~255) + j) * AA;
    float s = 0.f;
    #pragma unroll
    for (int d = 0; d < AA; ++d) s = fmaf(sv[d], fast_tanh(uj[d] + swa[d]), s);
    if (j == i) s = -10000.f;

    float e = __expf(s);
    if (i >= 1)
        out[1 + (((size_t)(i - 1) * BB + (bi >> 8)) * SS + j)] = e;

    float r = e;
    #pragma unroll
    for (int off = 32; off > 0; off >>= 1) r += __shfl_xor(r, off, 64);
    __shared__ float part[4];
    if ((j & 63) == 0) part[j >> 6] = r;
    __syncthreads();
    float tot = part[0] + part[1] + part[2] + part[3];

    if (j == heads[bi])
        ce[bi] = (i >= 1) ? (__logf(tot) - s) : 0.f;
}

// -------------------------------------------------------------------------
// Kernel 5: deterministic loss reduction: sum(ce)/B into out[0].
// -------------------------------------------------------------------------
__global__ __launch_bounds__(256) void k_loss(const float* __restrict__ ce,
                                              float* __restrict__ out)
{
    __shared__ float red[256];
    int t = threadIdx.x;
    float a = 0.f;
    for (int k = t; k < BB * SS; k += 256) a += ce[k];
    red[t] = a; __syncthreads();
    for (int off = 128; off > 0; off >>= 1) {
        if (t < off) red[t] += red[t + off];
        __syncthreads();
    }
    if (t == 0) out[0] = red[0] * (1.f / BB);
}

extern "C" void kernel_launch(void* const* d_in, const int* in_sizes, int n_in,
                              void* d_out, int out_size, void* d_ws, size_t ws_size,
                              hipStream_t stream)
{
    const int*   words = (const int*)  d_in[0];
    const int*   pos   = (const int*)  d_in[1];
    const float* morph = (const float*)d_in[2];
    const int*   heads = (const int*)  d_in[3];
    const float* wtab  = (const float*)d_in[4];
    const float* ptab  = (const float*)d_in[5];
    const float* Wxf   = (const float*)d_in[6];
    const float* Whf   = (const float*)d_in[7];
    const float* bf    = (const float*)d_in[8];
    const float* Wxb   = (const float*)d_in[9];
    const float* Whb   = (const float*)d_in[10];
    const float* bb    = (const float*)d_in[11];
    const float* Wu    = (const float*)d_in[12];
    const float* bu    = (const float*)d_in[13];
    const float* Ww    = (const float*)d_in[14];
    const float* bw    = (const float*)d_in[15];
    const float* v     = (const float*)d_in[16];
    float* out = (float*)d_out;

    // workspace layout (floats) -- xgf and xgb MUST stay adjacent (the lstm
    // prefetch overreads up to 4 steps past either end of its chain).
    float* xgf  = (float*)d_ws;                 // 8192*24
    float* xgb  = xgf  + (size_t)BB*SS*G4;      // 8192*24
    float* repr = xgb  + (size_t)BB*SS*G4;      // 8192*12
    float* ua   = repr + (size_t)BB*SS*2*HH;    // 8192*12
    float* wa   = ua   + (size_t)BB*SS*AA;      // 8192*12
    float* ce   = wa   + (size_t)BB*SS*AA;      // 8192

    k_embed_proj<<<(BB * SS) / EP_POS, 256, 0, stream>>>(words, pos, morph, wtab, ptab,
                                                         Wxf, bf, Wxb, bb, xgf, xgb);
    k_lstm<<<8, 512, 0, stream>>>(xgf, xgb, Whf, Whb, repr);
    k_uawa<<<(BB * SS) / 256, 256, 0, stream>>>(repr, Wu, bu, Ww, bw, ua, wa);
    k_score<<<BB * SS, 256, 0, stream>>>(ua, wa, v, heads, out, ce);
    k_loss<<<1, 256, 0, stream>>>(ce, out);
}

// Round 6
// 93.769 us; speedup vs baseline: 1.3096x; 1.3096x over previous
//
#include <hip/hip_runtime.h>
#include <hip/hip_bf16.h>

// Problem constants
#define BB 32
#define SS 256
#define DD 300
#define PDD 32
#define MM 66
#define FF 398      // D + PD + M
#define HH 6
#define G4 24       // 4*H
#define AA 12

__device__ __forceinline__ float fast_rcp(float x) { return __builtin_amdgcn_rcpf(x); }
__device__ __forceinline__ float sigmoidf_(float x) { return fast_rcp(1.f + __expf(-x)); }
__device__ __forceinline__ float fast_tanh(float x) {
    return 1.f - 2.f * fast_rcp(__expf(2.f * x) + 1.f);
}
__device__ __forceinline__ float bcast_lane(float x, int l) {
    return __int_as_float(__builtin_amdgcn_readlane(__float_as_int(x), l));
}

// -------------------------------------------------------------------------
// Kernel 1 (v3): embed+concat+input projection, both directions fused.
// 16 positions/block -> grid 512 (2 blocks/CU, 8 waves/CU).
// -------------------------------------------------------------------------
#define EP_POS 16
__global__ __launch_bounds__(256) void k_embed_proj(
    const int* __restrict__ words, const int* __restrict__ pos,
    const float* __restrict__ morph, const float* __restrict__ wtab,
    const float* __restrict__ ptab,
    const float* __restrict__ Wxf, const float* __restrict__ bfv,
    const float* __restrict__ Wxb, const float* __restrict__ bbv,
    float* __restrict__ xgf, float* __restrict__ xgb)
{
    __shared__ float sfeat[EP_POS * 100];   //  6.4 KB
    __shared__ float sW[48 * 100];          // 19.2 KB

    int t   = threadIdx.x;
    int bs0 = blockIdx.x * EP_POS;

    int cg = t & 15;         // col group: cols 3*cg .. 3*cg+2 (0..47)
    int p  = t >> 4;         // position 0..15
    float a0 = 0.f, a1 = 0.f, a2 = 0.f;

    for (int tile = 0; tile < 4; ++tile) {
        if (tile < 3) {
            for (int idx = t; idx < EP_POS * 25; idx += 256) {
                int pp = idx / 25, f = idx % 25;
                const float4* srcr = (const float4*)(wtab +
                    (size_t)words[bs0 + pp] * DD + tile * 100);
                ((float4*)sfeat)[pp * 25 + f] = srcr[f];
            }
        } else {
            for (int idx = t; idx < EP_POS * 100; idx += 256) {
                int pp = idx / 100, kk = idx % 100;
                float vv;
                if (kk < PDD)           vv = ptab[pos[bs0 + pp] * PDD + kk];
                else if (kk < PDD + MM) vv = morph[(size_t)(bs0 + pp) * MM + (kk - PDD)];
                else                    vv = 0.f;
                sfeat[pp * 100 + kk] = vv;
            }
        }
        for (int idx = t; idx < 2400; idx += 256) {
            int kk = idx / 24, j = idx % 24;
            int k = tile * 100 + kk;
            float wf = (k < FF) ? Wxf[k * G4 + j] : 0.f;
            float wb = (k < FF) ? Wxb[k * G4 + j] : 0.f;
            sW[j * 100 + kk]        = wf;
            sW[(24 + j) * 100 + kk] = wb;
        }
        __syncthreads();

        const float4* Fp = (const float4*)(sfeat + p * 100);
        const float4* W0 = (const float4*)(sW + (3 * cg + 0) * 100);
        const float4* W1 = (const float4*)(sW + (3 * cg + 1) * 100);
        const float4* W2 = (const float4*)(sW + (3 * cg + 2) * 100);
        #pragma unroll 5
        for (int q = 0; q < 25; ++q) {
            float4 f0 = Fp[q];
            float4 w0 = W0[q], w1 = W1[q], w2 = W2[q];
            a0 = fmaf(f0.x, w0.x, a0); a0 = fmaf(f0.y, w0.y, a0);
            a0 = fmaf(f0.z, w0.z, a0); a0 = fmaf(f0.w, w0.w, a0);
            a1 = fmaf(f0.x, w1.x, a1); a1 = fmaf(f0.y, w1.y, a1);
            a1 = fmaf(f0.z, w1.z, a1); a1 = fmaf(f0.w, w1.w, a1);
            a2 = fmaf(f0.x, w2.x, a2); a2 = fmaf(f0.y, w2.y, a2);
            a2 = fmaf(f0.z, w2.z, a2); a2 = fmaf(f0.w, w2.w, a2);
        }
        __syncthreads();
    }

    int c0  = 3 * cg;
    int dir = c0 >= 24 ? 1 : 0;
    int jj  = c0 - dir * 24;
    const float* bias = dir ? bbv : bfv;
    float*       xg   = dir ? xgb : xgf;
    float* o = xg + (size_t)(bs0 + p) * G4 + jj;
    o[0] = a0 + bias[jj]; o[1] = a1 + bias[jj + 1]; o[2] = a2 + bias[jj + 2];
}

// -------------------------------------------------------------------------
// Kernel 2 (v5): LSTM recurrence. One wave per (batch, direction), 64 CUs.
// xg fully staged in LDS (pre-reversed for bwd; +8 guard rows so prefetch
// needs no bounds check). Rotating 4-slot REGISTER prefetch from LDS: step
// t issues ds_reads for step t+4 -> 120cy LDS latency fully covered by ~4
// steps of compute. Gate dots are depth-4 trees, transcendental chains kept
// parallel. h -> LDS ring, bulk-coalesced copy at the end.
// -------------------------------------------------------------------------
__global__ __launch_bounds__(64) void k_lstm(
    const float* __restrict__ xgf, const float* __restrict__ xgb,
    const float* __restrict__ Whf, const float* __restrict__ Whb,
    float* __restrict__ repr)
{
    __shared__ float sxg[(SS + 8) * G4];    // 25344 B (8 zero guard rows)
    __shared__ float hbuf[SS * HH];         //  6144 B
    int blk = blockIdx.x;                   // 0..63
    int dir = blk >> 5;
    int b   = blk & 31;
    int lane = threadIdx.x;

    const float* xg = (dir ? xgb : xgf) + (size_t)b * SS * G4;
    const float* Wh = dir ? Whb : Whf;

    // stage xg -> LDS, rows reversed for bwd; zero the guard rows
    {
        const float4* src = (const float4*)xg;
        float4* dst = (float4*)sxg;
        #pragma unroll
        for (int u = 0; u < 24; ++u) {
            int d = lane + u * 64;          // float4 index 0..1535
            int row = d / 6, col = d - row * 6;
            int drow = dir ? (SS - 1 - row) : row;
            dst[drow * 6 + col] = src[d];
        }
        for (int g = lane; g < 8 * G4; g += 64) sxg[SS * G4 + g] = 0.f;
    }

    int k = lane % HH;                      // cell id (lanes >=6 duplicate)
    float wh0[HH], wh1[HH], wh2[HH], wh3[HH];
    #pragma unroll
    for (int m = 0; m < HH; ++m) {
        wh0[m] = Wh[m * G4 + 0 * HH + k];
        wh1[m] = Wh[m * G4 + 1 * HH + k];
        wh2[m] = Wh[m * G4 + 2 * HH + k];
        wh3[m] = Wh[m * G4 + 3 * HH + k];
    }
    float sh[HH];
    #pragma unroll
    for (int m = 0; m < HH; ++m) sh[m] = 0.f;
    float c = 0.f;
    bool wr = lane < HH;
    __syncthreads();

    const float* xb = sxg + k;

    // rotating 4-slot register prefetch
    float pgi[4], pgf[4], pgc[4], pgo[4];
    #pragma unroll
    for (int sl = 0; sl < 4; ++sl) {
        pgi[sl] = xb[sl * 24 + 0];  pgf[sl] = xb[sl * 24 + 6];
        pgc[sl] = xb[sl * 24 + 12]; pgo[sl] = xb[sl * 24 + 18];
    }

    #pragma unroll 1
    for (int t = 0; t < SS; t += 4) {
        #pragma unroll
        for (int sl = 0; sl < 4; ++sl) {
            float gi = pgi[sl], gf = pgf[sl], gc = pgc[sl], go = pgo[sl];
            // issue prefetch for step t+4+sl (guard rows make this safe)
            {
                const float* p = xb + (t + 4 + sl) * 24;
                pgi[sl] = p[0]; pgf[sl] = p[6]; pgc[sl] = p[12]; pgo[sl] = p[18];
            }
            // depth-4 gate trees
            float i01 = fmaf(sh[1], wh0[1], fmaf(sh[0], wh0[0], gi));
            float i23 = fmaf(sh[3], wh0[3], sh[2] * wh0[2]);
            float i45 = fmaf(sh[5], wh0[5], sh[4] * wh0[4]);
            gi = (i01 + i23) + i45;
            float f01 = fmaf(sh[1], wh1[1], fmaf(sh[0], wh1[0], gf));
            float f23 = fmaf(sh[3], wh1[3], sh[2] * wh1[2]);
            float f45 = fmaf(sh[5], wh1[5], sh[4] * wh1[4]);
            gf = (f01 + f23) + f45;
            float c01 = fmaf(sh[1], wh2[1], fmaf(sh[0], wh2[0], gc));
            float c23 = fmaf(sh[3], wh2[3], sh[2] * wh2[2]);
            float c45 = fmaf(sh[5], wh2[5], sh[4] * wh2[4]);
            gc = (c01 + c23) + c45;
            float o01 = fmaf(sh[1], wh3[1], fmaf(sh[0], wh3[0], go));
            float o23 = fmaf(sh[3], wh3[3], sh[2] * wh3[2]);
            float o45 = fmaf(sh[5], wh3[5], sh[4] * wh3[4]);
            go = (o01 + o23) + o45;

            c = fmaf(sigmoidf_(gf), c, sigmoidf_(gi) * fast_tanh(gc));
            float h = sigmoidf_(go) * fast_tanh(c);
            if (wr) hbuf[(t + sl) * HH + k] = h;
            #pragma unroll
            for (int m = 0; m < HH; ++m) sh[m] = bcast_lane(h, m);
        }
    }
    __syncthreads();

    // coalesced copy out (undo time order for bwd)
    #pragma unroll
    for (int u = 0; u < (SS * HH) / 64; ++u) {
        int idx = lane + u * 64;
        int tt = idx / 6, cc = idx - tt * 6;
        int s = dir ? (SS - 1 - tt) : tt;
        repr[((size_t)b * SS + s) * (2 * HH) + dir * HH + cc] = hbuf[idx];
    }
}

// -------------------------------------------------------------------------
// Kernel 3: ua = repr@Wu+bu ; wa = repr@Ww+bw. One thread per (b,s).
// -------------------------------------------------------------------------
__global__ __launch_bounds__(256) void k_uawa(
    const float* __restrict__ repr,
    const float* __restrict__ Wu, const float* __restrict__ bu,
    const float* __restrict__ Ww, const float* __restrict__ bw,
    float* __restrict__ ua, float* __restrict__ wa)
{
    int bs = blockIdx.x * blockDim.x + threadIdx.x;   // 0..8191
    float r[AA];
    #pragma unroll
    for (int e = 0; e < AA; ++e) r[e] = repr[(size_t)bs * AA + e];
    #pragma unroll
    for (int d = 0; d < AA; ++d) {
        float au = bu[d], aw = bw[d];
        #pragma unroll
        for (int e = 0; e < AA; ++e) {
            au = fmaf(r[e], Wu[e * AA + d], au);
            aw = fmaf(r[e], Ww[e * AA + d], aw);
        }
        ua[(size_t)bs * AA + d] = au;
        wa[(size_t)bs * AA + d] = aw;
    }
}

// -------------------------------------------------------------------------
// Kernel 4: arc scores + sum-exp + CE partials + exp table.
// -------------------------------------------------------------------------
__global__ __launch_bounds__(256) void k_score(
    const float* __restrict__ ua, const float* __restrict__ wa,
    const float* __restrict__ v, const int* __restrict__ heads,
    float* __restrict__ out, float* __restrict__ ce)
{
    int bi = blockIdx.x;            // b*S + i
    int i  = bi & 255;
    int j  = threadIdx.x;

    __shared__ float swa[AA], sv[AA];
    if (j < AA) { swa[j] = wa[(size_t)bi * AA + j]; sv[j] = v[j]; }
    __syncthreads();

    const float* uj = ua + ((size_t)(bi & ~255) + j) * AA;
    float s = 0.f;
    #pragma unroll
    for (int d = 0; d < AA; ++d) s = fmaf(sv[d], fast_tanh(uj[d] + swa[d]), s);
    if (j == i) s = -10000.f;

    float e = __expf(s);
    if (i >= 1)
        out[1 + (((size_t)(i - 1) * BB + (bi >> 8)) * SS + j)] = e;

    float r = e;
    #pragma unroll
    for (int off = 32; off > 0; off >>= 1) r += __shfl_xor(r, off, 64);
    __shared__ float part[4];
    if ((j & 63) == 0) part[j >> 6] = r;
    __syncthreads();
    float tot = part[0] + part[1] + part[2] + part[3];

    if (j == heads[bi])
        ce[bi] = (i >= 1) ? (__logf(tot) - s) : 0.f;
}

// -------------------------------------------------------------------------
// Kernel 5: deterministic loss reduction: sum(ce)/B into out[0].
// -------------------------------------------------------------------------
__global__ __launch_bounds__(256) void k_loss(const float* __restrict__ ce,
                                              float* __restrict__ out)
{
    __shared__ float red[256];
    int t = threadIdx.x;
    float a = 0.f;
    for (int k = t; k < BB * SS; k += 256) a += ce[k];
    red[t] = a; __syncthreads();
    for (int off = 128; off > 0; off >>= 1) {
        if (t < off) red[t] += red[t + off];
        __syncthreads();
    }
    if (t == 0) out[0] = red[0] * (1.f / BB);
}

extern "C" void kernel_launch(void* const* d_in, const int* in_sizes, int n_in,
                              void* d_out, int out_size, void* d_ws, size_t ws_size,
                              hipStream_t stream)
{
    const int*   words = (const int*)  d_in[0];
    const int*   pos   = (const int*)  d_in[1];
    const float* morph = (const float*)d_in[2];
    const int*   heads = (const int*)  d_in[3];
    const float* wtab  = (const float*)d_in[4];
    const float* ptab  = (const float*)d_in[5];
    const float* Wxf   = (const float*)d_in[6];
    const float* Whf   = (const float*)d_in[7];
    const float* bf    = (const float*)d_in[8];
    const float* Wxb   = (const float*)d_in[9];
    const float* Whb   = (const float*)d_in[10];
    const float* bb    = (const float*)d_in[11];
    const float* Wu    = (const float*)d_in[12];
    const float* bu    = (const float*)d_in[13];
    const float* Ww    = (const float*)d_in[14];
    const float* bw    = (const float*)d_in[15];
    const float* v     = (const float*)d_in[16];
    float* out = (float*)d_out;

    // workspace layout (floats)
    float* xgf  = (float*)d_ws;                 // 8192*24
    float* xgb  = xgf  + (size_t)BB*SS*G4;      // 8192*24
    float* repr = xgb  + (size_t)BB*SS*G4;      // 8192*12
    float* ua   = repr + (size_t)BB*SS*2*HH;    // 8192*12
    float* wa   = ua   + (size_t)BB*SS*AA;      // 8192*12
    float* ce   = wa   + (size_t)BB*SS*AA;      // 8192

    k_embed_proj<<<(BB * SS) / EP_POS, 256, 0, stream>>>(words, pos, morph, wtab, ptab,
                                                         Wxf, bf, Wxb, bb, xgf, xgb);
    k_lstm<<<BB * 2, 64, 0, stream>>>(xgf, xgb, Whf, Whb, repr);
    k_uawa<<<(BB * SS) / 256, 256, 0, stream>>>(repr, Wu, bu, Ww, bw, ua, wa);
    k_score<<<BB * SS, 256, 0, stream>>>(ua, wa, v, heads, out, ce);
    k_loss<<<1, 256, 0, stream>>>(ce, out);
}

// Round 7
// 86.407 us; speedup vs baseline: 1.4212x; 1.0852x over previous
//
#include <hip/hip_runtime.h>
#include <hip/hip_bf16.h>

// Problem constants
#define BB 32
#define SS 256
#define DD 300
#define PDD 32
#define MM 66
#define FF 398      // D + PD + M
#define HH 6
#define G4 24       // 4*H
#define AA 12

__device__ __forceinline__ float fast_rcp(float x) { return __builtin_amdgcn_rcpf(x); }
__device__ __forceinline__ float fast_tanh(float x) {
    return 1.f - 2.f * fast_rcp(__expf(2.f * x) + 1.f);
}
__device__ __forceinline__ float bcast_lane(float x, int l) {
    return __int_as_float(__builtin_amdgcn_readlane(__float_as_int(x), l));
}
__device__ __forceinline__ float bperm(int byteaddr, float v) {
    return __int_as_float(__builtin_amdgcn_ds_bpermute(byteaddr, __float_as_int(v)));
}

// -------------------------------------------------------------------------
// Kernel 1 (v4): embed+concat+input projection, both dirs fused.
// EP_POS=32, 2-pos x 3-col register tile: 5 b128 LDS reads per 24 fma
// (halves LDS-pipe cycles vs v3's 4 reads / 12 fma). Grid 256.
// -------------------------------------------------------------------------
#define EP_POS 32
__global__ __launch_bounds__(256) void k_embed_proj(
    const int* __restrict__ words, const int* __restrict__ pos,
    const float* __restrict__ morph, const float* __restrict__ wtab,
    const float* __restrict__ ptab,
    const float* __restrict__ Wxf, const float* __restrict__ bfv,
    const float* __restrict__ Wxb, const float* __restrict__ bbv,
    float* __restrict__ xgf, float* __restrict__ xgb)
{
    __shared__ float sfeat[EP_POS * 100];   // 12.8 KB
    __shared__ float sW[48 * 100];          // 19.2 KB

    int t   = threadIdx.x;
    int bs0 = blockIdx.x * EP_POS;

    int cg   = t & 15;       // col group: cols 3*cg .. 3*cg+2 (0..47)
    int slot = t >> 4;       // position slot 0..15 -> pos slot, slot+16
    float a00 = 0.f, a01 = 0.f, a02 = 0.f;
    float a10 = 0.f, a11 = 0.f, a12 = 0.f;

    for (int tile = 0; tile < 4; ++tile) {
        if (tile < 3) {
            for (int idx = t; idx < EP_POS * 25; idx += 256) {
                int pp = idx / 25, f = idx % 25;
                const float4* srcr = (const float4*)(wtab +
                    (size_t)words[bs0 + pp] * DD + tile * 100);
                ((float4*)sfeat)[pp * 25 + f] = srcr[f];
            }
        } else {
            for (int idx = t; idx < EP_POS * 100; idx += 256) {
                int pp = idx / 100, kk = idx % 100;
                float vv;
                if (kk < PDD)           vv = ptab[pos[bs0 + pp] * PDD + kk];
                else if (kk < PDD + MM) vv = morph[(size_t)(bs0 + pp) * MM + (kk - PDD)];
                else                    vv = 0.f;
                sfeat[pp * 100 + kk] = vv;
            }
        }
        for (int idx = t; idx < 2400; idx += 256) {
            int kk = idx / 24, j = idx % 24;
            int k = tile * 100 + kk;
            float wf = (k < FF) ? Wxf[k * G4 + j] : 0.f;
            float wb = (k < FF) ? Wxb[k * G4 + j] : 0.f;
            sW[j * 100 + kk]        = wf;
            sW[(24 + j) * 100 + kk] = wb;
        }
        __syncthreads();

        const float4* F0 = (const float4*)(sfeat + slot * 100);
        const float4* F1 = (const float4*)(sfeat + (slot + 16) * 100);
        const float4* W0 = (const float4*)(sW + (3 * cg + 0) * 100);
        const float4* W1 = (const float4*)(sW + (3 * cg + 1) * 100);
        const float4* W2 = (const float4*)(sW + (3 * cg + 2) * 100);
        #pragma unroll 5
        for (int q = 0; q < 25; ++q) {
            float4 f0 = F0[q], f1 = F1[q];
            float4 w0 = W0[q], w1 = W1[q], w2 = W2[q];
            a00 = fmaf(f0.x, w0.x, a00); a00 = fmaf(f0.y, w0.y, a00);
            a00 = fmaf(f0.z, w0.z, a00); a00 = fmaf(f0.w, w0.w, a00);
            a01 = fmaf(f0.x, w1.x, a01); a01 = fmaf(f0.y, w1.y, a01);
            a01 = fmaf(f0.z, w1.z, a01); a01 = fmaf(f0.w, w1.w, a01);
            a02 = fmaf(f0.x, w2.x, a02); a02 = fmaf(f0.y, w2.y, a02);
            a02 = fmaf(f0.z, w2.z, a02); a02 = fmaf(f0.w, w2.w, a02);
            a10 = fmaf(f1.x, w0.x, a10); a10 = fmaf(f1.y, w0.y, a10);
            a10 = fmaf(f1.z, w0.z, a10); a10 = fmaf(f1.w, w0.w, a10);
            a11 = fmaf(f1.x, w1.x, a11); a11 = fmaf(f1.y, w1.y, a11);
            a11 = fmaf(f1.z, w1.z, a11); a11 = fmaf(f1.w, w1.w, a11);
            a12 = fmaf(f1.x, w2.x, a12); a12 = fmaf(f1.y, w2.y, a12);
            a12 = fmaf(f1.z, w2.z, a12); a12 = fmaf(f1.w, w2.w, a12);
        }
        __syncthreads();
    }

    int c0  = 3 * cg;                 // never straddles the 24 boundary
    int dir = c0 >= 24 ? 1 : 0;
    int jj  = c0 - dir * 24;
    const float* bias = dir ? bbv : bfv;
    float*       xg   = dir ? xgb : xgf;
    float b0 = bias[jj], b1 = bias[jj + 1], b2 = bias[jj + 2];
    float* o0 = xg + (size_t)(bs0 + slot) * G4 + jj;
    float* o1 = xg + (size_t)(bs0 + slot + 16) * G4 + jj;
    o0[0] = a00 + b0; o0[1] = a01 + b1; o0[2] = a02 + b2;
    o1[0] = a10 + b0; o1[1] = a11 + b1; o1[2] = a12 + b2;
}

// -------------------------------------------------------------------------
// Kernel 2 (v7): LSTM recurrence, GATE-LANE layout.
// Lane l owns gate j = l%24 (keras order: i 0-5, f 6-11, c 12-17, o 18-23).
// Per step for ALL 24 gates at once: 6 fma dot, then one shared nonlinearity
// block (exp2 with per-lane +-log2e constant; fmaf(B,e,A)*rcp(1+e) selects
// sigmoid/tanh). Cell update: 4 parallel ds_bpermutes gather sigma_i/f/o,
// tau_c to each lane's cell (cell = l%6; dup lanes compute identical values
// -> deterministic). ~36 issue slots/step vs ~60 in the cell layout.
// -------------------------------------------------------------------------
__global__ __launch_bounds__(64) void k_lstm(
    const float* __restrict__ xgf, const float* __restrict__ xgb,
    const float* __restrict__ Whf, const float* __restrict__ Whb,
    float* __restrict__ repr)
{
    __shared__ float sxg[(SS + 8) * G4];    // 8 zero guard rows for prefetch
    __shared__ float hbuf[SS * HH];
    int blk = blockIdx.x;                   // 0..63
    int dir = blk >> 5;
    int b   = blk & 31;
    int lane = threadIdx.x;

    const float* xg = (dir ? xgb : xgf) + (size_t)b * SS * G4;
    const float* Wh = dir ? Whb : Whf;

    // stage xg -> LDS, rows reversed for bwd; zero guard rows
    {
        const float4* src = (const float4*)xg;
        float4* dst = (float4*)sxg;
        #pragma unroll
        for (int u = 0; u < 24; ++u) {
            int d = lane + u * 64;          // float4 index 0..1535
            int row = d / 6, col = d - row * 6;
            int drow = dir ? (SS - 1 - row) : row;
            dst[drow * 6 + col] = src[d];
        }
        for (int g = lane; g < 8 * G4; g += 64) sxg[SS * G4 + g] = 0.f;
    }

    int j    = lane % G4;                   // gate id 0..23
    int cell = lane % HH;                   // cell id 0..5
    int type = j / HH;                      // 0=i 1=f 2=c 3=o

    float wh[HH];
    #pragma unroll
    for (int m = 0; m < HH; ++m) wh[m] = Wh[m * G4 + j];

    const float L2E = 1.4426950408889634f;
    float kk = (type == 2) ? 2.f * L2E : -L2E;   // tanh: e^{2x}; sig: e^{-x}
    float Bc = (type == 2) ? 1.f : 0.f;          // tanh num = e-1; sig num = 1
    float Ac = (type == 2) ? -1.f : 1.f;

    // bpermute byte addresses (loop-invariant)
    int ai = cell * 4;
    int af = (HH + cell) * 4;
    int ac = (2 * HH + cell) * 4;
    int ao = (3 * HH + cell) * 4;

    float sh[HH];
    #pragma unroll
    for (int m = 0; m < HH; ++m) sh[m] = 0.f;
    float c = 0.f;
    __syncthreads();

    const float* xb = sxg + j;

    // 4-slot rotating register prefetch (1 ds_read per step)
    float pg[4];
    #pragma unroll
    for (int sl = 0; sl < 4; ++sl) pg[sl] = xb[sl * G4];

    #pragma unroll 1
    for (int t = 0; t < SS; t += 4) {
        #pragma unroll
        for (int sl = 0; sl < 4; ++sl) {
            float x = pg[sl];
            pg[sl] = xb[(t + 4 + sl) * G4];      // prefetch (guard rows cover tail)

            #pragma unroll
            for (int m = 0; m < HH; ++m) x = fmaf(sh[m], wh[m], x);

            // per-lane nonlinearity: sigmoid or tanh via one exp2 + rcp
            float e  = __builtin_amdgcn_exp2f(x * kk);
            float vv = fmaf(Bc, e, Ac) * fast_rcp(1.f + e);

            // gather this cell's four gate values (parallel, one latency)
            float vi = bperm(ai, vv);
            float vf = bperm(af, vv);
            float vc = bperm(ac, vv);
            float vo = bperm(ao, vv);

            c = fmaf(vf, c, vi * vc);
            float ec = __builtin_amdgcn_exp2f(c * (2.f * L2E));
            float h  = (ec - 1.f) * fast_rcp(ec + 1.f) * vo;

            hbuf[(t + sl) * HH + cell] = h;      // dup lanes write same value
            #pragma unroll
            for (int m = 0; m < HH; ++m) sh[m] = bcast_lane(h, m);
        }
    }
    __syncthreads();

    // coalesced copy out (undo time order for bwd)
    #pragma unroll
    for (int u = 0; u < (SS * HH) / 64; ++u) {
        int idx = lane + u * 64;
        int tt = idx / 6, cc = idx - tt * 6;
        int s = dir ? (SS - 1 - tt) : tt;
        repr[((size_t)b * SS + s) * (2 * HH) + dir * HH + cc] = hbuf[idx];
    }
}

// -------------------------------------------------------------------------
// Kernel 3: ua = repr@Wu+bu ; wa = repr@Ww+bw. One thread per (b,s).
// -------------------------------------------------------------------------
__global__ __launch_bounds__(256) void k_uawa(
    const float* __restrict__ repr,
    const float* __restrict__ Wu, const float* __restrict__ bu,
    const float* __restrict__ Ww, const float* __restrict__ bw,
    float* __restrict__ ua, float* __restrict__ wa)
{
    int bs = blockIdx.x * blockDim.x + threadIdx.x;   // 0..8191
    float r[AA];
    #pragma unroll
    for (int e = 0; e < AA; ++e) r[e] = repr[(size_t)bs * AA + e];
    #pragma unroll
    for (int d = 0; d < AA; ++d) {
        float au = bu[d], aw = bw[d];
        #pragma unroll
        for (int e = 0; e < AA; ++e) {
            au = fmaf(r[e], Wu[e * AA + d], au);
            aw = fmaf(r[e], Ww[e * AA + d], aw);
        }
        ua[(size_t)bs * AA + d] = au;
        wa[(size_t)bs * AA + d] = aw;
    }
}

// -------------------------------------------------------------------------
// Kernel 4: arc scores + sum-exp + CE partials + exp table.
// -------------------------------------------------------------------------
__global__ __launch_bounds__(256) void k_score(
    const float* __restrict__ ua, const float* __restrict__ wa,
    const float* __restrict__ v, const int* __restrict__ heads,
    float* __restrict__ out, float* __restrict__ ce)
{
    int bi = blockIdx.x;            // b*S + i
    int i  = bi & 255;
    int j  = threadIdx.x;

    __shared__ float swa[AA], sv[AA];
    if (j < AA) { swa[j] = wa[(size_t)bi * AA + j]; sv[j] = v[j]; }
    __syncthreads();

    const float* uj = ua + ((size_t)(bi & ~255) + j) * AA;
    float s = 0.f;
    #pragma unroll
    for (int d = 0; d < AA; ++d) s = fmaf(sv[d], fast_tanh(uj[d] + swa[d]), s);
    if (j == i) s = -10000.f;

    float e = __expf(s);
    if (i >= 1)
        out[1 + (((size_t)(i - 1) * BB + (bi >> 8)) * SS + j)] = e;

    float r = e;
    #pragma unroll
    for (int off = 32; off > 0; off >>= 1) r += __shfl_xor(r, off, 64);
    __shared__ float part[4];
    if ((j & 63) == 0) part[j >> 6] = r;
    __syncthreads();
    float tot = part[0] + part[1] + part[2] + part[3];

    if (j == heads[bi])
        ce[bi] = (i >= 1) ? (__logf(tot) - s) : 0.f;
}

// -------------------------------------------------------------------------
// Kernel 5: deterministic loss reduction: sum(ce)/B into out[0].
// -------------------------------------------------------------------------
__global__ __launch_bounds__(256) void k_loss(const float* __restrict__ ce,
                                              float* __restrict__ out)
{
    __shared__ float red[256];
    int t = threadIdx.x;
    float a = 0.f;
    for (int k = t; k < BB * SS; k += 256) a += ce[k];
    red[t] = a; __syncthreads();
    for (int off = 128; off > 0; off >>= 1) {
        if (t < off) red[t] += red[t + off];
        __syncthreads();
    }
    if (t == 0) out[0] = red[0] * (1.f / BB);
}

extern "C" void kernel_launch(void* const* d_in, const int* in_sizes, int n_in,
                              void* d_out, int out_size, void* d_ws, size_t ws_size,
                              hipStream_t stream)
{
    const int*   words = (const int*)  d_in[0];
    const int*   pos   = (const int*)  d_in[1];
    const float* morph = (const float*)d_in[2];
    const int*   heads = (const int*)  d_in[3];
    const float* wtab  = (const float*)d_in[4];
    const float* ptab  = (const float*)d_in[5];
    const float* Wxf   = (const float*)d_in[6];
    const float* Whf   = (const float*)d_in[7];
    const float* bf    = (const float*)d_in[8];
    const float* Wxb   = (const float*)d_in[9];
    const float* Whb   = (const float*)d_in[10];
    const float* bb    = (const float*)d_in[11];
    const float* Wu    = (const float*)d_in[12];
    const float* bu    = (const float*)d_in[13];
    const float* Ww    = (const float*)d_in[14];
    const float* bw    = (const float*)d_in[15];
    const float* v     = (const float*)d_in[16];
    float* out = (float*)d_out;

    // workspace layout (floats)
    float* xgf  = (float*)d_ws;                 // 8192*24
    float* xgb  = xgf  + (size_t)BB*SS*G4;      // 8192*24
    float* repr = xgb  + (size_t)BB*SS*G4;      // 8192*12
    float* ua   = repr + (size_t)BB*SS*2*HH;    // 8192*12
    float* wa   = ua   + (size_t)BB*SS*AA;      // 8192*12
    float* ce   = wa   + (size_t)BB*SS*AA;      // 8192

    k_embed_proj<<<(BB * SS) / EP_POS, 256, 0, stream>>>(words, pos, morph, wtab, ptab,
                                                         Wxf, bf, Wxb, bb, xgf, xgb);
    k_lstm<<<BB * 2, 64, 0, stream>>>(xgf, xgb, Whf, Whb, repr);
    k_uawa<<<(BB * SS) / 256, 256, 0, stream>>>(repr, Wu, bu, Ww, bw, ua, wa);
    k_score<<<BB * SS, 256, 0, stream>>>(ua, wa, v, heads, out, ce);
    k_loss<<<1, 256, 0, stream>>>(ce, out);
}